// Round 9
// baseline (3781.743 us; speedup 1.0000x reference)
//
#include <hip/hip_runtime.h>

// SentenceEncodingRNN2: 2-layer BiLSTM (T=256,B=128,D=300,H=256) + attention pooling.
// Round 18: wave-specialized fusion. R17 post-mortem: same-wave proj fusion is
//   program-order serial -- only load LATENCY hides under a spin; issue/ALU/barrier
//   cost added ~1.8us/step (4.77 vs R11 2.98). Fix: 512-thread blocks; waves 0-3 =
//   exact R11/R17 lstm protocol (128-VGPR resident weights, parity-ring spin);
//   waves 4-7 = independent proj engine (reg-prefetch -> LDS -> 48 MFMA/step,
//   epilogue every 16 steps into 76-slot xg ring). CU scheduler overlaps waves
//   (m114): proj streams while lstm spins on L3. 2 uniform barriers/step (outside
//   divergent branches; spins capped -> no deadlock). LDS 62KB; launch_bounds(512,2)
//   caps VGPR at 256. Warmup proj y=0..63, attn_gemm/attn_final unchanged.

#define T_ 256
#define B_ 128
#define D_ 300
#define H_ 256
#define G4H 1024   // 4*H
#define H2 512     // 2*H
#define LDK 40     // proj/attn LDS k-stride in bf16 (80 B rows)
#define LDA 264    // lstm A-tile LDS k-stride in bf16 (256+8)
#define XGS 76     // xg ring slots
#define RSLOTS 4   // h-exchange ring slots

typedef __attribute__((ext_vector_type(8))) short bf16x8;
typedef __attribute__((ext_vector_type(4))) short short4v;
typedef __attribute__((ext_vector_type(4))) float f32x4;

#define MFMA16(a, b, c) __builtin_amdgcn_mfma_f32_16x16x32_bf16(a, b, c, 0, 0, 0)
#define ATOM_ST(p, v) __hip_atomic_store((p), (v), __ATOMIC_RELAXED, __HIP_MEMORY_SCOPE_AGENT)
#define ATOM_LD(p) __hip_atomic_load((p), __ATOMIC_RELAXED, __HIP_MEMORY_SCOPE_AGENT)

// ---------------- helpers ----------------
__device__ __forceinline__ float sigf(float x) { return 1.f / (1.f + __expf(-x)); }
__device__ __forceinline__ float tanhfast(float x) { return 2.f / (1.f + __expf(-2.f * x)) - 1.f; }

__device__ __forceinline__ short hi_bf16(float x) {
  return (short)(__float_as_uint(x) >> 16);
}
__device__ __forceinline__ short lo_bf16(float x) {
  float lo = x - __uint_as_float(__float_as_uint(x) & 0xFFFF0000u);
  return (short)(__float_as_uint(lo) >> 16);
}

__device__ __forceinline__ void split_f4(const float4 v, short* hp, short* lp) {
  short4v h, l;
  h.x = hi_bf16(v.x); l.x = lo_bf16(v.x);
  h.y = hi_bf16(v.y); l.y = lo_bf16(v.y);
  h.z = hi_bf16(v.z); l.z = lo_bf16(v.z);
  h.w = hi_bf16(v.w); l.w = lo_bf16(v.w);
  *(short4v*)hp = h;
  *(short4v*)lp = l;
}

__device__ __forceinline__ void split8(const float4 v0, const float4 v1,
                                       bf16x8* hp, bf16x8* lp) {
  bf16x8 h, l;
  h[0] = hi_bf16(v0.x); l[0] = lo_bf16(v0.x);
  h[1] = hi_bf16(v0.y); l[1] = lo_bf16(v0.y);
  h[2] = hi_bf16(v0.z); l[2] = lo_bf16(v0.z);
  h[3] = hi_bf16(v0.w); l[3] = lo_bf16(v0.w);
  h[4] = hi_bf16(v1.x); l[4] = lo_bf16(v1.x);
  h[5] = hi_bf16(v1.y); l[5] = lo_bf16(v1.y);
  h[6] = hi_bf16(v1.z); l[6] = lo_bf16(v1.z);
  h[7] = hi_bf16(v1.w); l[7] = lo_bf16(v1.w);
  *hp = h; *lp = l;
}

// ---------------- dual-direction projection GEMM (standalone, y=0..63) -----------
__global__ __launch_bounds__(256, 2) void proj_gemm2(
    const float* __restrict__ X,
    const float* __restrict__ W0, const float* __restrict__ W1,
    const float* __restrict__ b1f, const float* __restrict__ b2f,
    const float* __restrict__ b1r, const float* __restrict__ b2r,
    float* __restrict__ C0, float* __restrict__ C1,
    int N, int K, const int* __restrict__ lengths, int t0)
{
  __shared__ short Xh[128 * LDK], Xl[128 * LDK];
  __shared__ short Wh[128 * LDK], Wl[128 * LDK];
  const int rev = blockIdx.z;
  const float* __restrict__ W = rev ? W1 : W0;
  const float* __restrict__ bias1 = rev ? b1r : b1f;
  const float* __restrict__ bias2 = rev ? b2r : b2f;
  float* __restrict__ C = rev ? C1 : C0;

  const int tid = threadIdx.x;
  const int m0 = blockIdx.y * 128, n0 = blockIdx.x * 128;
  const int s_step = t0 + blockIdx.y;

  const int sr = tid >> 3;
  const int sc = (tid & 7) * 4;
  const float* px[4];
  const float* pw[4];
#pragma unroll
  for (int p = 0; p < 4; p++) {
    const int r = sr + p * 32;          // r == batch index within tile
    int ss = s_step;
    if (rev) {
      int lb = lengths[r]; if (lb < 1) lb = 1;
      ss = (s_step < lb) ? (lb - 1 - s_step) : s_step;
    }
    px[p] = X + (size_t)(ss * 128 + r) * K;
    pw[p] = W + (size_t)(n0 + r) * K;
  }

  const int lane = tid & 63, w = tid >> 6;
  const int mb = (w & 1) * 64, nb = (w >> 1) * 64;
  const int r16 = lane & 15, quad = lane >> 4;

  f32x4 acc[4][4];
#pragma unroll
  for (int i = 0; i < 4; i++)
#pragma unroll
    for (int j = 0; j < 4; j++) acc[i][j] = (f32x4){0.f, 0.f, 0.f, 0.f};

  for (int k0 = 0; k0 < K; k0 += 32) {
    const int gk = k0 + sc;
    const bool kin = (gk < K);          // K % 4 == 0 -> whole float4 in/out
#pragma unroll
    for (int p = 0; p < 4; p++) {
      float4 xv = {0.f, 0.f, 0.f, 0.f}, wv = {0.f, 0.f, 0.f, 0.f};
      if (kin) { xv = *(const float4*)(px[p] + gk); wv = *(const float4*)(pw[p] + gk); }
      const int ro = (sr + p * 32) * LDK + sc;
      split_f4(xv, &Xh[ro], &Xl[ro]);
      split_f4(wv, &Wh[ro], &Wl[ro]);
    }
    __syncthreads();

    bf16x8 ah[4], al[4], bh[4], bl[4];
#pragma unroll
    for (int mt = 0; mt < 4; mt++) {
      const int ro = (mb + mt * 16 + r16) * LDK + quad * 8;
      ah[mt] = *(const bf16x8*)&Xh[ro];
      al[mt] = *(const bf16x8*)&Xl[ro];
    }
#pragma unroll
    for (int nt = 0; nt < 4; nt++) {
      const int ro = (nb + nt * 16 + r16) * LDK + quad * 8;
      bh[nt] = *(const bf16x8*)&Wh[ro];
      bl[nt] = *(const bf16x8*)&Wl[ro];
    }
#pragma unroll
    for (int mt = 0; mt < 4; mt++)
#pragma unroll
      for (int nt = 0; nt < 4; nt++) {
        acc[mt][nt] = __builtin_amdgcn_mfma_f32_16x16x32_bf16(ah[mt], bh[nt], acc[mt][nt], 0, 0, 0);
        acc[mt][nt] = __builtin_amdgcn_mfma_f32_16x16x32_bf16(ah[mt], bl[nt], acc[mt][nt], 0, 0, 0);
        acc[mt][nt] = __builtin_amdgcn_mfma_f32_16x16x32_bf16(al[mt], bh[nt], acc[mt][nt], 0, 0, 0);
      }
    __syncthreads();
  }

  float bsum[4];
#pragma unroll
  for (int nt = 0; nt < 4; nt++) {
    const int col = n0 + nb + nt * 16 + r16;
    bsum[nt] = bias1[col] + bias2[col];
  }
#pragma unroll
  for (int mt = 0; mt < 4; mt++) {
    const int row = m0 + mb + mt * 16 + quad * 4;
#pragma unroll
    for (int nt = 0; nt < 4; nt++) {
      const int col = n0 + nb + nt * 16 + r16;
      float* Cp = C + (size_t)row * N + col;
#pragma unroll
      for (int reg = 0; reg < 4; reg++)
        Cp[(size_t)reg * N] = acc[mt][nt][reg] + bsum[nt];
    }
  }
}

// ---------------- attention score GEMM, split-bf16 MFMA, fused tanh*ctx ----------
__global__ __launch_bounds__(256, 2) void attn_gemm(
    const float* __restrict__ X, const float* __restrict__ W,
    const float* __restrict__ mlp_b, const float* __restrict__ ctx,
    float* __restrict__ scores, int M, int N, int K)
{
  __shared__ short Xh[128 * LDK], Xl[128 * LDK];
  __shared__ short Wh[128 * LDK], Wl[128 * LDK];
  const int tid = threadIdx.x;
  const int m0 = blockIdx.y * 128, n0 = blockIdx.x * 128;

  const int sr = tid >> 3;
  const int sc = (tid & 7) * 4;
  const float* px[4];
  const float* pw[4];
#pragma unroll
  for (int p = 0; p < 4; p++) {
    px[p] = X + (size_t)(m0 + sr + p * 32) * K;
    pw[p] = W + (size_t)(n0 + sr + p * 32) * K;
  }

  const int lane = tid & 63, w = tid >> 6;
  const int mb = (w & 1) * 64, nb = (w >> 1) * 64;
  const int r16 = lane & 15, quad = lane >> 4;

  f32x4 acc[4][4];
#pragma unroll
  for (int i = 0; i < 4; i++)
#pragma unroll
    for (int j = 0; j < 4; j++) acc[i][j] = (f32x4){0.f, 0.f, 0.f, 0.f};

  for (int k0 = 0; k0 < K; k0 += 32) {
    const int gk = k0 + sc;
#pragma unroll
    for (int p = 0; p < 4; p++) {
      float4 xv = *(const float4*)(px[p] + gk);
      float4 wv = *(const float4*)(pw[p] + gk);
      const int ro = (sr + p * 32) * LDK + sc;
      split_f4(xv, &Xh[ro], &Xl[ro]);
      split_f4(wv, &Wh[ro], &Wl[ro]);
    }
    __syncthreads();

    bf16x8 ah[4], al[4], bh[4], bl[4];
#pragma unroll
    for (int mt = 0; mt < 4; mt++) {
      const int ro = (mb + mt * 16 + r16) * LDK + quad * 8;
      ah[mt] = *(const bf16x8*)&Xh[ro];
      al[mt] = *(const bf16x8*)&Xl[ro];
    }
#pragma unroll
    for (int nt = 0; nt < 4; nt++) {
      const int ro = (nb + nt * 16 + r16) * LDK + quad * 8;
      bh[nt] = *(const bf16x8*)&Wh[ro];
      bl[nt] = *(const bf16x8*)&Wl[ro];
    }
#pragma unroll
    for (int mt = 0; mt < 4; mt++)
#pragma unroll
      for (int nt = 0; nt < 4; nt++) {
        acc[mt][nt] = __builtin_amdgcn_mfma_f32_16x16x32_bf16(ah[mt], bh[nt], acc[mt][nt], 0, 0, 0);
        acc[mt][nt] = __builtin_amdgcn_mfma_f32_16x16x32_bf16(ah[mt], bl[nt], acc[mt][nt], 0, 0, 0);
        acc[mt][nt] = __builtin_amdgcn_mfma_f32_16x16x32_bf16(al[mt], bh[nt], acc[mt][nt], 0, 0, 0);
      }
    __syncthreads();
  }

  float bb4[4], cc4[4];
#pragma unroll
  for (int nt = 0; nt < 4; nt++) {
    const int col = n0 + nb + nt * 16 + r16;
    bb4[nt] = mlp_b[col];
    cc4[nt] = ctx[col];
  }
#pragma unroll
  for (int mt = 0; mt < 4; mt++) {
#pragma unroll
    for (int reg = 0; reg < 4; reg++) {
      float ssum = 0.f;
#pragma unroll
      for (int nt = 0; nt < 4; nt++)
        ssum += tanhfast(acc[mt][nt][reg] + bb4[nt]) * cc4[nt];
      ssum += __shfl_xor(ssum, 1);
      ssum += __shfl_xor(ssum, 2);
      ssum += __shfl_xor(ssum, 4);
      ssum += __shfl_xor(ssum, 8);
      if (r16 == 0)
        atomicAdd(&scores[m0 + mb + mt * 16 + quad * 4 + reg], ssum);
    }
  }
}

// ---------------- fused LSTM + wave-specialized proj -- R18 ----------------------
// 256 blocks x 512 threads, blk = s*32 + d*16 + g (partners same (d,g) -> same XCD).
// Waves 0-3 (tid<256): R11/R17 lstm protocol, 256 steps, parity ring (4 slots).
// Waves 4-7 (tid>=256): proj engine; tiles (n0=s*128, dir=d, y=64+16*wj+g, wj<12),
//   1 k-iter/step (reg-prefetched), epilogue at ki==15 -> xg slot y%XGS (margin 49).
// 2 uniform barriers/step: B1 (gbuf / PX-PW staged), B2 (A restaged / LDS consumed).
__global__ __launch_bounds__(512, 2) void lstm_fused(
    float* __restrict__ xgF, float* __restrict__ xgR,
    const float* __restrict__ XSRC,
    const float* __restrict__ whF, const float* __restrict__ whR,
    const float* __restrict__ wihF, const float* __restrict__ wihR,
    const float* __restrict__ b1f, const float* __restrict__ b2f,
    const float* __restrict__ b1r, const float* __restrict__ b2r,
    const int* __restrict__ lengths, float* __restrict__ hout,
    float* __restrict__ ring, int K)
{
  __shared__ short Ah[16 * LDA], Al[16 * LDA];   // rows 0-7 batches, 8-15 zero
  __shared__ float gbuf[8 * 128];
  __shared__ short PXh[128 * LDK], PXl[128 * LDK];
  __shared__ short PWh[128 * LDK], PWl[128 * LDK];

  const int tid = threadIdx.x;
  const int blk = blockIdx.x;
  const int s = blk >> 5;
  const int d = (blk >> 4) & 1;
  const int g = blk & 15;
  const bool is_lstm = (tid < 256);
  float* __restrict__ xgd = d ? xgR : xgF;
  const float* __restrict__ wh = d ? whR : whF;
  const float* __restrict__ wih = d ? wihR : wihF;
  const float* __restrict__ bias1 = d ? b1r : b1f;
  const float* __restrict__ bias2 = d ? b2r : b2f;
  unsigned* __restrict__ ring32 = (unsigned*)ring;
  const int KITERS = (K + 31) >> 5;

  // ---- lstm-side mappings (tid < 256) ----
  const int w = tid >> 6;              // wave 0..3 == gate index
  const int lane = tid & 63;
  const int r16 = lane & 15, quad = lane >> 4;
  const int cb = (tid >> 5) & 7;
  const int hl = tid & 31;
  const int b = g * 8 + cb;
  const int hdim = s * 32 + hl;
  const int k0 = hl * 8;

  // ---- proj-side mappings (tid >= 256) ----
  const int pt = tid & 255;
  const int sr = pt >> 3;              // staging row 0..31
  const int sc = (pt & 7) * 4;
  const int w2 = pt >> 6;              // proj wave 0..3
  const int pmb = (w2 & 1) * 64, pnb = (w2 >> 1) * 64;
  const int pr16 = (pt & 63) & 15, pquad = (pt & 63) >> 4;
  const int n0 = s * 128;

  // ---- zero A (all threads) ----
  {
    int* za = (int*)Ah;
    int* zb = (int*)Al;
    for (int i = tid; i < (16 * LDA) / 2; i += 512) { za[i] = 0; zb[i] = 0; }
  }

  // ---- lstm init: weights (128 VGPR), c, lengths, x(0) ----
  bf16x8 bh[2][8], bl[2][8];
  float c = 0.f;
  int lb = 1;
  float x0 = 0.f, x1 = 0.f, x2 = 0.f, x3 = 0.f;
  // ---- proj init: lengths per staging row, prefetch regs, accumulators ----
  int lenp[4];
  float4 pfX[4], pfW[4];
  f32x4 pacc[4][4];

  if (is_lstm) {
#pragma unroll
    for (int nt = 0; nt < 2; nt++)
#pragma unroll
      for (int kt = 0; kt < 8; kt++) {
        const float* wr = wh + (size_t)(w * 256 + s * 32 + nt * 16 + r16) * 256
                             + kt * 32 + quad * 8;
        float4 v0 = *(const float4*)(wr);
        float4 v1 = *(const float4*)(wr + 4);
        split8(v0, v1, &bh[nt][kt], &bl[nt][kt]);
      }
    lb = lengths[b]; if (lb < 1) lb = 1;
    const float* xr0 = xgd + (size_t)b * 1024 + hdim;
    x0 = ATOM_LD(xr0); x1 = ATOM_LD(xr0 + 256);
    x2 = ATOM_LD(xr0 + 512); x3 = ATOM_LD(xr0 + 768);
  } else {
#pragma unroll
    for (int p = 0; p < 4; p++) {
      int lv = lengths[sr + p * 32]; if (lv < 1) lv = 1;
      lenp[p] = lv;
    }
#pragma unroll
    for (int i = 0; i < 4; i++)
#pragma unroll
      for (int j = 0; j < 4; j++) pacc[i][j] = (f32x4){0.f, 0.f, 0.f, 0.f};
    // prologue prefetch: t=0 -> wj=0, ki=0, y=64+g
    {
      const int y = 64 + g;
      const int gk = sc;                // ki=0
#pragma unroll
      for (int p = 0; p < 4; p++) {
        const int r = sr + p * 32;
        int ss = y;
        if (d) ss = (y < lenp[p]) ? (lenp[p] - 1 - y) : y;
        pfX[p] = *(const float4*)(XSRC + ((size_t)ss * 128 + r) * K + gk);
        pfW[p] = *(const float4*)(wih + (size_t)(n0 + r) * K + gk);
      }
    }
  }
  __syncthreads();

  for (int t = 0; t < T_; t++) {
    const bool last = (t == T_ - 1);

    // ================= PHASE A =================
    if (is_lstm) {
      // lstm MFMA gate matvec: 48 MFMAs, 6 independent chains
      f32x4 aH0 = {0.f,0.f,0.f,0.f}, aM0 = {0.f,0.f,0.f,0.f}, aL0 = {0.f,0.f,0.f,0.f};
      f32x4 aH1 = {0.f,0.f,0.f,0.f}, aM1 = {0.f,0.f,0.f,0.f}, aL1 = {0.f,0.f,0.f,0.f};
#pragma unroll
      for (int kt = 0; kt < 8; kt++) {
        const int ro = r16 * LDA + kt * 32 + quad * 8;
        bf16x8 ahf = *(const bf16x8*)&Ah[ro];
        bf16x8 alf = *(const bf16x8*)&Al[ro];
        aH0 = MFMA16(ahf, bh[0][kt], aH0);
        aM0 = MFMA16(ahf, bl[0][kt], aM0);
        aL0 = MFMA16(alf, bh[0][kt], aL0);
        aH1 = MFMA16(ahf, bh[1][kt], aH1);
        aM1 = MFMA16(ahf, bl[1][kt], aM1);
        aL1 = MFMA16(alf, bh[1][kt], aL1);
      }
      if (quad < 2) {
#pragma unroll
        for (int reg = 0; reg < 4; reg++) {
          gbuf[(quad * 4 + reg) * 128 + w * 32 + r16]      = aH0[reg] + aM0[reg] + aL0[reg];
          gbuf[(quad * 4 + reg) * 128 + w * 32 + 16 + r16] = aH1[reg] + aM1[reg] + aL1[reg];
        }
      }
    } else {
      // proj: stage prefetched regs -> LDS (k-iter of step t)
      if (t < 192) {
        const int ki = t & 15;
        if (ki < KITERS) {
#pragma unroll
          for (int p = 0; p < 4; p++) {
            const int gk = ki * 32 + sc;
            const int ro = (sr + p * 32) * LDK + sc;
            float4 xv = {0.f,0.f,0.f,0.f}, wv = {0.f,0.f,0.f,0.f};
            if (gk < K) { xv = pfX[p]; wv = pfW[p]; }
            split_f4(xv, &PXh[ro], &PXl[ro]);
            split_f4(wv, &PWh[ro], &PWl[ro]);
          }
        }
      }
    }
    __syncthreads();   // B1: gbuf ready (lstm) / PX,PW staged (proj)

    // ================= PHASE B =================
    if (is_lstm) {
      // cell update
      const float gi = gbuf[cb * 128 +       hl] + x0;
      const float gf = gbuf[cb * 128 +  32 + hl] + x1;
      const float gg = gbuf[cb * 128 +  64 + hl] + x2;
      const float go = gbuf[cb * 128 +  96 + hl] + x3;
      const float si = sigf(gi), sf = sigf(gf);
      const float tg = tanhfast(gg), so = sigf(go);
      c = sf * c + si * tg;
      const float h = so * tanhfast(c);
      if (!last) {
        const unsigned hu = (unsigned)(unsigned short)hi_bf16(h);
        const unsigned lu = (unsigned)(unsigned short)lo_bf16(h);
        const unsigned pv = (hu << 16) | (lu & 0xFFFEu) | (unsigned)((t >> 2) & 1);
        ATOM_ST(&ring32[(((t & 3) * 2 + d) * 128 + b) * 256 + hdim], pv);
      }
      const int tin = d ? ((t < lb) ? (lb - 1 - t) : t) : t;
      hout[((size_t)tin * 128 + b) * 512 + d * 256 + hdim] = h;

      if (!last) {
        // prefetch x(t+1) from xg ring (L3-coherent)
        const int ns = (t + 1) % XGS;
        const float* xn = xgd + ((size_t)ns * 128 + b) * 1024 + hdim;
        const float nx0 = ATOM_LD(xn), nx1 = ATOM_LD(xn + 256);
        const float nx2 = ATOM_LD(xn + 512), nx3 = ATOM_LD(xn + 768);

        // spin on ring (direct data poll, parity check), then restage A
        const unsigned* ru = ring32 + (((t & 3) * 2 + d) * 128 + g * 8 + cb) * 256 + k0;
        const unsigned par = (unsigned)((t >> 2) & 1);
        unsigned uv[8];
        int it = 0;
        for (;;) {
          bool ok = true;
#pragma unroll
          for (int j = 0; j < 8; j++) {
            uv[j] = ATOM_LD(&ru[j]);
            ok &= ((uv[j] & 1u) == par);
          }
          if (ok || ++it >= 100000) break;
        }
        bf16x8 hv, lv;
#pragma unroll
        for (int j = 0; j < 8; j++) {
          hv[j] = (short)(uv[j] >> 16);
          lv[j] = (short)(uv[j] & 0xFFFFu);
        }
        *(bf16x8*)&Ah[cb * LDA + k0] = hv;
        *(bf16x8*)&Al[cb * LDA + k0] = lv;

        x0 = nx0; x1 = nx1; x2 = nx2; x3 = nx3;
      }
    } else {
      // proj: consume LDS -> 48 MFMAs; epilogue at ki==15; prefetch next k-iter
      if (t < 192) {
        const int ki = t & 15;
        if (ki < KITERS) {
          bf16x8 pah[4], pal[4], pbh[4], pbl[4];
#pragma unroll
          for (int mt = 0; mt < 4; mt++) {
            const int ro = (pmb + mt * 16 + pr16) * LDK + pquad * 8;
            pah[mt] = *(const bf16x8*)&PXh[ro];
            pal[mt] = *(const bf16x8*)&PXl[ro];
          }
#pragma unroll
          for (int nt = 0; nt < 4; nt++) {
            const int ro = (pnb + nt * 16 + pr16) * LDK + pquad * 8;
            pbh[nt] = *(const bf16x8*)&PWh[ro];
            pbl[nt] = *(const bf16x8*)&PWl[ro];
          }
#pragma unroll
          for (int mt = 0; mt < 4; mt++)
#pragma unroll
            for (int nt = 0; nt < 4; nt++) {
              pacc[mt][nt] = MFMA16(pah[mt], pbh[nt], pacc[mt][nt]);
              pacc[mt][nt] = MFMA16(pah[mt], pbl[nt], pacc[mt][nt]);
              pacc[mt][nt] = MFMA16(pal[mt], pbh[nt], pacc[mt][nt]);
            }
        }
        if (ki == 15) {
          const int y = 64 + (t >> 4) * 16 + g;
          const int yslot = y % XGS;
          float bsum[4];
#pragma unroll
          for (int nt = 0; nt < 4; nt++) {
            const int col = n0 + pnb + nt * 16 + pr16;
            bsum[nt] = bias1[col] + bias2[col];
          }
#pragma unroll
          for (int mt = 0; mt < 4; mt++) {
            const int row = pmb + mt * 16 + pquad * 4;
#pragma unroll
            for (int nt = 0; nt < 4; nt++) {
              const int col = n0 + pnb + nt * 16 + pr16;
              float* Cp = xgd + ((size_t)yslot * 128 + row) * 1024 + col;
#pragma unroll
              for (int reg = 0; reg < 4; reg++)
                ATOM_ST(&Cp[(size_t)reg * 1024], pacc[mt][nt][reg] + bsum[nt]);
              pacc[mt][nt] = (f32x4){0.f, 0.f, 0.f, 0.f};
            }
          }
        }
      }
      // prefetch for step t+1 (latency hides through B2 + next phase A)
      const int tn = t + 1;
      if (tn < 192) {
        const int kin = tn & 15;
        if (kin < KITERS) {
          const int y = 64 + (tn >> 4) * 16 + g;
          const int gk = kin * 32 + sc;
          if (gk < K) {
#pragma unroll
            for (int p = 0; p < 4; p++) {
              const int r = sr + p * 32;
              int ss = y;
              if (d) ss = (y < lenp[p]) ? (lenp[p] - 1 - y) : y;
              pfX[p] = *(const float4*)(XSRC + ((size_t)ss * 128 + r) * K + gk);
              pfW[p] = *(const float4*)(wih + (size_t)(n0 + r) * K + gk);
            }
          }
        }
      }
    }
    __syncthreads();   // B2: A restaged (lstm) / LDS consumed (proj)
  }
}

// ---------------- masked softmax over t + weighted sum ----------------
__global__ __launch_bounds__(256) void attn_final(
    const float* __restrict__ h2, const float* __restrict__ scores,
    const int* __restrict__ lengths, float* __restrict__ out)
{
  __shared__ float sl[256];
  __shared__ float red[256];
  const int b = blockIdx.x, tid = threadIdx.x;
  int lb = lengths[b]; if (lb < 1) lb = 1;
  const float sc = scores[(size_t)tid * 128 + b];
  const bool valid = (tid < lb);
  red[tid] = valid ? sc : -1e30f;
  __syncthreads();
  for (int off = 128; off > 0; off >>= 1) {
    if (tid < off) red[tid] = fmaxf(red[tid], red[tid + off]);
    __syncthreads();
  }
  const float mx = red[0];
  __syncthreads();
  const float p = valid ? __expf(sc - mx) : 0.f;
  red[tid] = p;
  __syncthreads();
  for (int off = 128; off > 0; off >>= 1) {
    if (tid < off) red[tid] += red[tid + off];
    __syncthreads();
  }
  const float inv = 1.f / red[0];
  __syncthreads();
  sl[tid] = p * inv;
  __syncthreads();

  float ax = 0.f, ay = 0.f;
  const int dd = tid * 2;
  for (int t = 0; t < 256; t++) {
    const float w = sl[t];
    if (w != 0.f) {
      const float* row = h2 + ((size_t)t * 128 + b) * 512 + dd;
      ax += w * row[0];
      ay += w * row[1];
    }
  }
  float2 r; r.x = ax; r.y = ay;
  *(float2*)(out + (size_t)b * 512 + dd) = r;
}

// ---------------- launch ----------------
extern "C" void kernel_launch(void* const* d_in, const int* in_sizes, int n_in,
                              void* d_out, int out_size, void* d_ws, size_t ws_size,
                              hipStream_t stream) {
  (void)in_sizes; (void)n_in; (void)out_size; (void)ws_size;
  const float* x        = (const float*)d_in[0];
  const int*   lengths  = (const int*)d_in[1];
  const float* w_ih_l0  = (const float*)d_in[2];
  const float* w_hh_l0  = (const float*)d_in[3];
  const float* b_ih_l0  = (const float*)d_in[4];
  const float* b_hh_l0  = (const float*)d_in[5];
  const float* w_ih_l0r = (const float*)d_in[6];
  const float* w_hh_l0r = (const float*)d_in[7];
  const float* b_ih_l0r = (const float*)d_in[8];
  const float* b_hh_l0r = (const float*)d_in[9];
  const float* w_ih_l1  = (const float*)d_in[10];
  const float* w_hh_l1  = (const float*)d_in[11];
  const float* b_ih_l1  = (const float*)d_in[12];
  const float* b_hh_l1  = (const float*)d_in[13];
  const float* w_ih_l1r = (const float*)d_in[14];
  const float* w_hh_l1r = (const float*)d_in[15];
  const float* b_ih_l1r = (const float*)d_in[16];
  const float* b_hh_l1r = (const float*)d_in[17];
  const float* mlp_w    = (const float*)d_in[18];
  const float* mlp_b    = (const float*)d_in[19];
  const float* ctx      = (const float*)d_in[20];
  float* out = (float*)d_out;

  // workspace layout (floats): ~215 MB
  float* ws = (float*)d_ws;
  const size_t XG76  = (size_t)XGS * B_ * G4H;        // 9,961,472
  const size_t H_SZ  = (size_t)T_ * B_ * H2;          // 16,777,216
  const size_t RINGF = (size_t)RSLOTS * 2 * B_ * H_;  // 262,144
  float* xgF    = ws;
  float* xgR    = xgF + XG76;
  float* h1     = xgR + XG76;
  float* h2     = h1 + H_SZ;
  float* ring   = h2 + H_SZ;
  float* scores = ring + RINGF;                       // 32,768

  (void)hipMemsetAsync(scores, 0, 32768 * 4, stream);

  dim3 blk(256);
  const dim3 pgrid(G4H / 128, 64, 2);   // standalone proj: y = 0..63, both dirs

  // ---- layer 0 ----
  proj_gemm2<<<pgrid, blk, 0, stream>>>(x, w_ih_l0, w_ih_l0r,
                                        b_ih_l0, b_hh_l0, b_ih_l0r, b_hh_l0r,
                                        xgF, xgR, G4H, D_, lengths, 0);
  (void)hipMemsetAsync(ring, 0xFF, RINGF * 4, stream);   // sentinel (parity=1)
  lstm_fused<<<256, dim3(512), 0, stream>>>(xgF, xgR, x, w_hh_l0, w_hh_l0r,
                                            w_ih_l0, w_ih_l0r,
                                            b_ih_l0, b_hh_l0, b_ih_l0r, b_hh_l0r,
                                            lengths, h1, ring, D_);
  // ---- layer 1 ----
  proj_gemm2<<<pgrid, blk, 0, stream>>>(h1, w_ih_l1, w_ih_l1r,
                                        b_ih_l1, b_hh_l1, b_ih_l1r, b_hh_l1r,
                                        xgF, xgR, G4H, H2, lengths, 0);
  (void)hipMemsetAsync(ring, 0xFF, RINGF * 4, stream);
  lstm_fused<<<256, dim3(512), 0, stream>>>(xgF, xgR, h1, w_hh_l1, w_hh_l1r,
                                            w_ih_l1, w_ih_l1r,
                                            b_ih_l1, b_hh_l1, b_ih_l1r, b_hh_l1r,
                                            lengths, h2, ring, H2);
  // ---- attention ----
  attn_gemm<<<dim3(H2 / 128, (T_ * B_) / 128), blk, 0, stream>>>(h2, mlp_w, mlp_b, ctx, scores, T_ * B_, H2, H2);
  attn_final<<<B_, blk, 0, stream>>>(h2, scores, lengths, out);
}

// Round 10
// 3751.008 us; speedup vs baseline: 1.0082x; 1.0082x over previous
//
#include <hip/hip_runtime.h>

// SentenceEncodingRNN2: 2-layer BiLSTM (T=256,B=128,D=300,H=256) + attention pooling.
// Round 19: R18 with the launch-bounds fix. R18 post-mortem: __launch_bounds__(512,2)
//   capped VGPR at 128 (< the 128 weight VGPRs + proj regs) -> scratch spills
//   (WRITE_SIZE 327MB -> 1.5GB), slow blocks, cross-g drift past the xg margin ->
//   absmax 0.002. Wave-specialization itself never tested. Fix: (512,1) -- compiler
//   enforces only launchability (8 waves/CU => <=256 VGPR), weights resident again.
//   Structure unchanged: waves 0-3 = R11 lstm protocol (parity ring spin); waves
//   4-7 = proj engine (reg-prefetch -> LDS -> 48 MFMA/step, epilogue every 16 steps
//   into 76-slot xg ring). 2 uniform barriers/step. Warmup proj y=0..63,
//   attn_gemm/attn_final unchanged.

#define T_ 256
#define B_ 128
#define D_ 300
#define H_ 256
#define G4H 1024   // 4*H
#define H2 512     // 2*H
#define LDK 40     // proj/attn LDS k-stride in bf16 (80 B rows)
#define LDA 264    // lstm A-tile LDS k-stride in bf16 (256+8)
#define XGS 76     // xg ring slots
#define RSLOTS 4   // h-exchange ring slots

typedef __attribute__((ext_vector_type(8))) short bf16x8;
typedef __attribute__((ext_vector_type(4))) short short4v;
typedef __attribute__((ext_vector_type(4))) float f32x4;

#define MFMA16(a, b, c) __builtin_amdgcn_mfma_f32_16x16x32_bf16(a, b, c, 0, 0, 0)
#define ATOM_ST(p, v) __hip_atomic_store((p), (v), __ATOMIC_RELAXED, __HIP_MEMORY_SCOPE_AGENT)
#define ATOM_LD(p) __hip_atomic_load((p), __ATOMIC_RELAXED, __HIP_MEMORY_SCOPE_AGENT)

// ---------------- helpers ----------------
__device__ __forceinline__ float sigf(float x) { return 1.f / (1.f + __expf(-x)); }
__device__ __forceinline__ float tanhfast(float x) { return 2.f / (1.f + __expf(-2.f * x)) - 1.f; }

__device__ __forceinline__ short hi_bf16(float x) {
  return (short)(__float_as_uint(x) >> 16);
}
__device__ __forceinline__ short lo_bf16(float x) {
  float lo = x - __uint_as_float(__float_as_uint(x) & 0xFFFF0000u);
  return (short)(__float_as_uint(lo) >> 16);
}

__device__ __forceinline__ void split_f4(const float4 v, short* hp, short* lp) {
  short4v h, l;
  h.x = hi_bf16(v.x); l.x = lo_bf16(v.x);
  h.y = hi_bf16(v.y); l.y = lo_bf16(v.y);
  h.z = hi_bf16(v.z); l.z = lo_bf16(v.z);
  h.w = hi_bf16(v.w); l.w = lo_bf16(v.w);
  *(short4v*)hp = h;
  *(short4v*)lp = l;
}

__device__ __forceinline__ void split8(const float4 v0, const float4 v1,
                                       bf16x8* hp, bf16x8* lp) {
  bf16x8 h, l;
  h[0] = hi_bf16(v0.x); l[0] = lo_bf16(v0.x);
  h[1] = hi_bf16(v0.y); l[1] = lo_bf16(v0.y);
  h[2] = hi_bf16(v0.z); l[2] = lo_bf16(v0.z);
  h[3] = hi_bf16(v0.w); l[3] = lo_bf16(v0.w);
  h[4] = hi_bf16(v1.x); l[4] = lo_bf16(v1.x);
  h[5] = hi_bf16(v1.y); l[5] = lo_bf16(v1.y);
  h[6] = hi_bf16(v1.z); l[6] = lo_bf16(v1.z);
  h[7] = hi_bf16(v1.w); l[7] = lo_bf16(v1.w);
  *hp = h; *lp = l;
}

// ---------------- dual-direction projection GEMM (standalone, y=0..63) -----------
__global__ __launch_bounds__(256, 2) void proj_gemm2(
    const float* __restrict__ X,
    const float* __restrict__ W0, const float* __restrict__ W1,
    const float* __restrict__ b1f, const float* __restrict__ b2f,
    const float* __restrict__ b1r, const float* __restrict__ b2r,
    float* __restrict__ C0, float* __restrict__ C1,
    int N, int K, const int* __restrict__ lengths, int t0)
{
  __shared__ short Xh[128 * LDK], Xl[128 * LDK];
  __shared__ short Wh[128 * LDK], Wl[128 * LDK];
  const int rev = blockIdx.z;
  const float* __restrict__ W = rev ? W1 : W0;
  const float* __restrict__ bias1 = rev ? b1r : b1f;
  const float* __restrict__ bias2 = rev ? b2r : b2f;
  float* __restrict__ C = rev ? C1 : C0;

  const int tid = threadIdx.x;
  const int m0 = blockIdx.y * 128, n0 = blockIdx.x * 128;
  const int s_step = t0 + blockIdx.y;

  const int sr = tid >> 3;
  const int sc = (tid & 7) * 4;
  const float* px[4];
  const float* pw[4];
#pragma unroll
  for (int p = 0; p < 4; p++) {
    const int r = sr + p * 32;          // r == batch index within tile
    int ss = s_step;
    if (rev) {
      int lb = lengths[r]; if (lb < 1) lb = 1;
      ss = (s_step < lb) ? (lb - 1 - s_step) : s_step;
    }
    px[p] = X + (size_t)(ss * 128 + r) * K;
    pw[p] = W + (size_t)(n0 + r) * K;
  }

  const int lane = tid & 63, w = tid >> 6;
  const int mb = (w & 1) * 64, nb = (w >> 1) * 64;
  const int r16 = lane & 15, quad = lane >> 4;

  f32x4 acc[4][4];
#pragma unroll
  for (int i = 0; i < 4; i++)
#pragma unroll
    for (int j = 0; j < 4; j++) acc[i][j] = (f32x4){0.f, 0.f, 0.f, 0.f};

  for (int k0 = 0; k0 < K; k0 += 32) {
    const int gk = k0 + sc;
    const bool kin = (gk < K);          // K % 4 == 0 -> whole float4 in/out
#pragma unroll
    for (int p = 0; p < 4; p++) {
      float4 xv = {0.f, 0.f, 0.f, 0.f}, wv = {0.f, 0.f, 0.f, 0.f};
      if (kin) { xv = *(const float4*)(px[p] + gk); wv = *(const float4*)(pw[p] + gk); }
      const int ro = (sr + p * 32) * LDK + sc;
      split_f4(xv, &Xh[ro], &Xl[ro]);
      split_f4(wv, &Wh[ro], &Wl[ro]);
    }
    __syncthreads();

    bf16x8 ah[4], al[4], bh[4], bl[4];
#pragma unroll
    for (int mt = 0; mt < 4; mt++) {
      const int ro = (mb + mt * 16 + r16) * LDK + quad * 8;
      ah[mt] = *(const bf16x8*)&Xh[ro];
      al[mt] = *(const bf16x8*)&Xl[ro];
    }
#pragma unroll
    for (int nt = 0; nt < 4; nt++) {
      const int ro = (nb + nt * 16 + r16) * LDK + quad * 8;
      bh[nt] = *(const bf16x8*)&Wh[ro];
      bl[nt] = *(const bf16x8*)&Wl[ro];
    }
#pragma unroll
    for (int mt = 0; mt < 4; mt++)
#pragma unroll
      for (int nt = 0; nt < 4; nt++) {
        acc[mt][nt] = __builtin_amdgcn_mfma_f32_16x16x32_bf16(ah[mt], bh[nt], acc[mt][nt], 0, 0, 0);
        acc[mt][nt] = __builtin_amdgcn_mfma_f32_16x16x32_bf16(ah[mt], bl[nt], acc[mt][nt], 0, 0, 0);
        acc[mt][nt] = __builtin_amdgcn_mfma_f32_16x16x32_bf16(al[mt], bh[nt], acc[mt][nt], 0, 0, 0);
      }
    __syncthreads();
  }

  float bsum[4];
#pragma unroll
  for (int nt = 0; nt < 4; nt++) {
    const int col = n0 + nb + nt * 16 + r16;
    bsum[nt] = bias1[col] + bias2[col];
  }
#pragma unroll
  for (int mt = 0; mt < 4; mt++) {
    const int row = m0 + mb + mt * 16 + quad * 4;
#pragma unroll
    for (int nt = 0; nt < 4; nt++) {
      const int col = n0 + nb + nt * 16 + r16;
      float* Cp = C + (size_t)row * N + col;
#pragma unroll
      for (int reg = 0; reg < 4; reg++)
        Cp[(size_t)reg * N] = acc[mt][nt][reg] + bsum[nt];
    }
  }
}

// ---------------- attention score GEMM, split-bf16 MFMA, fused tanh*ctx ----------
__global__ __launch_bounds__(256, 2) void attn_gemm(
    const float* __restrict__ X, const float* __restrict__ W,
    const float* __restrict__ mlp_b, const float* __restrict__ ctx,
    float* __restrict__ scores, int M, int N, int K)
{
  __shared__ short Xh[128 * LDK], Xl[128 * LDK];
  __shared__ short Wh[128 * LDK], Wl[128 * LDK];
  const int tid = threadIdx.x;
  const int m0 = blockIdx.y * 128, n0 = blockIdx.x * 128;

  const int sr = tid >> 3;
  const int sc = (tid & 7) * 4;
  const float* px[4];
  const float* pw[4];
#pragma unroll
  for (int p = 0; p < 4; p++) {
    px[p] = X + (size_t)(m0 + sr + p * 32) * K;
    pw[p] = W + (size_t)(n0 + sr + p * 32) * K;
  }

  const int lane = tid & 63, w = tid >> 6;
  const int mb = (w & 1) * 64, nb = (w >> 1) * 64;
  const int r16 = lane & 15, quad = lane >> 4;

  f32x4 acc[4][4];
#pragma unroll
  for (int i = 0; i < 4; i++)
#pragma unroll
    for (int j = 0; j < 4; j++) acc[i][j] = (f32x4){0.f, 0.f, 0.f, 0.f};

  for (int k0 = 0; k0 < K; k0 += 32) {
    const int gk = k0 + sc;
#pragma unroll
    for (int p = 0; p < 4; p++) {
      float4 xv = *(const float4*)(px[p] + gk);
      float4 wv = *(const float4*)(pw[p] + gk);
      const int ro = (sr + p * 32) * LDK + sc;
      split_f4(xv, &Xh[ro], &Xl[ro]);
      split_f4(wv, &Wh[ro], &Wl[ro]);
    }
    __syncthreads();

    bf16x8 ah[4], al[4], bh[4], bl[4];
#pragma unroll
    for (int mt = 0; mt < 4; mt++) {
      const int ro = (mb + mt * 16 + r16) * LDK + quad * 8;
      ah[mt] = *(const bf16x8*)&Xh[ro];
      al[mt] = *(const bf16x8*)&Xl[ro];
    }
#pragma unroll
    for (int nt = 0; nt < 4; nt++) {
      const int ro = (nb + nt * 16 + r16) * LDK + quad * 8;
      bh[nt] = *(const bf16x8*)&Wh[ro];
      bl[nt] = *(const bf16x8*)&Wl[ro];
    }
#pragma unroll
    for (int mt = 0; mt < 4; mt++)
#pragma unroll
      for (int nt = 0; nt < 4; nt++) {
        acc[mt][nt] = __builtin_amdgcn_mfma_f32_16x16x32_bf16(ah[mt], bh[nt], acc[mt][nt], 0, 0, 0);
        acc[mt][nt] = __builtin_amdgcn_mfma_f32_16x16x32_bf16(ah[mt], bl[nt], acc[mt][nt], 0, 0, 0);
        acc[mt][nt] = __builtin_amdgcn_mfma_f32_16x16x32_bf16(al[mt], bh[nt], acc[mt][nt], 0, 0, 0);
      }
    __syncthreads();
  }

  float bb4[4], cc4[4];
#pragma unroll
  for (int nt = 0; nt < 4; nt++) {
    const int col = n0 + nb + nt * 16 + r16;
    bb4[nt] = mlp_b[col];
    cc4[nt] = ctx[col];
  }
#pragma unroll
  for (int mt = 0; mt < 4; mt++) {
#pragma unroll
    for (int reg = 0; reg < 4; reg++) {
      float ssum = 0.f;
#pragma unroll
      for (int nt = 0; nt < 4; nt++)
        ssum += tanhfast(acc[mt][nt][reg] + bb4[nt]) * cc4[nt];
      ssum += __shfl_xor(ssum, 1);
      ssum += __shfl_xor(ssum, 2);
      ssum += __shfl_xor(ssum, 4);
      ssum += __shfl_xor(ssum, 8);
      if (r16 == 0)
        atomicAdd(&scores[m0 + mb + mt * 16 + quad * 4 + reg], ssum);
    }
  }
}

// ---------------- fused LSTM + wave-specialized proj -- R19 ----------------------
// 256 blocks x 512 threads, blk = s*32 + d*16 + g (partners same (d,g) -> same XCD).
// launch_bounds(512,1): launchability-only VGPR cap (<=256) -> weights resident.
// Waves 0-3 (tid<256): R11/R17 lstm protocol, 256 steps, parity ring (4 slots).
// Waves 4-7 (tid>=256): proj engine; tiles (n0=s*128, dir=d, y=64+16*wj+g, wj<12),
//   1 k-iter/step (reg-prefetched), epilogue at ki==15 -> xg slot y%XGS (margin 48+g).
// 2 uniform barriers/step: B1 (gbuf / PX-PW staged), B2 (A restaged / LDS consumed).
__global__ __launch_bounds__(512, 1) void lstm_fused(
    float* __restrict__ xgF, float* __restrict__ xgR,
    const float* __restrict__ XSRC,
    const float* __restrict__ whF, const float* __restrict__ whR,
    const float* __restrict__ wihF, const float* __restrict__ wihR,
    const float* __restrict__ b1f, const float* __restrict__ b2f,
    const float* __restrict__ b1r, const float* __restrict__ b2r,
    const int* __restrict__ lengths, float* __restrict__ hout,
    float* __restrict__ ring, int K)
{
  __shared__ short Ah[16 * LDA], Al[16 * LDA];   // rows 0-7 batches, 8-15 zero
  __shared__ float gbuf[8 * 128];
  __shared__ short PXh[128 * LDK], PXl[128 * LDK];
  __shared__ short PWh[128 * LDK], PWl[128 * LDK];

  const int tid = threadIdx.x;
  const int blk = blockIdx.x;
  const int s = blk >> 5;
  const int d = (blk >> 4) & 1;
  const int g = blk & 15;
  const bool is_lstm = (tid < 256);
  float* __restrict__ xgd = d ? xgR : xgF;
  const float* __restrict__ wh = d ? whR : whF;
  const float* __restrict__ wih = d ? wihR : wihF;
  const float* __restrict__ bias1 = d ? b1r : b1f;
  const float* __restrict__ bias2 = d ? b2r : b2f;
  unsigned* __restrict__ ring32 = (unsigned*)ring;
  const int KITERS = (K + 31) >> 5;

  // ---- lstm-side mappings (tid < 256) ----
  const int w = tid >> 6;              // wave 0..3 == gate index
  const int lane = tid & 63;
  const int r16 = lane & 15, quad = lane >> 4;
  const int cb = (tid >> 5) & 7;
  const int hl = tid & 31;
  const int b = g * 8 + cb;
  const int hdim = s * 32 + hl;
  const int k0 = hl * 8;

  // ---- proj-side mappings (tid >= 256) ----
  const int pt = tid & 255;
  const int sr = pt >> 3;              // staging row 0..31
  const int sc = (pt & 7) * 4;
  const int w2 = pt >> 6;              // proj wave 0..3
  const int pmb = (w2 & 1) * 64, pnb = (w2 >> 1) * 64;
  const int pr16 = (pt & 63) & 15, pquad = (pt & 63) >> 4;
  const int n0 = s * 128;

  // ---- zero A (all threads) ----
  {
    int* za = (int*)Ah;
    int* zb = (int*)Al;
    for (int i = tid; i < (16 * LDA) / 2; i += 512) { za[i] = 0; zb[i] = 0; }
  }

  // ---- lstm init: weights (128 VGPR), c, lengths, x(0) ----
  bf16x8 bh[2][8], bl[2][8];
  float c = 0.f;
  int lb = 1;
  float x0 = 0.f, x1 = 0.f, x2 = 0.f, x3 = 0.f;
  // ---- proj init: lengths per staging row, prefetch regs, accumulators ----
  int lenp[4];
  float4 pfX[4], pfW[4];
  f32x4 pacc[4][4];

  if (is_lstm) {
#pragma unroll
    for (int nt = 0; nt < 2; nt++)
#pragma unroll
      for (int kt = 0; kt < 8; kt++) {
        const float* wr = wh + (size_t)(w * 256 + s * 32 + nt * 16 + r16) * 256
                             + kt * 32 + quad * 8;
        float4 v0 = *(const float4*)(wr);
        float4 v1 = *(const float4*)(wr + 4);
        split8(v0, v1, &bh[nt][kt], &bl[nt][kt]);
      }
    lb = lengths[b]; if (lb < 1) lb = 1;
    const float* xr0 = xgd + (size_t)b * 1024 + hdim;
    x0 = ATOM_LD(xr0); x1 = ATOM_LD(xr0 + 256);
    x2 = ATOM_LD(xr0 + 512); x3 = ATOM_LD(xr0 + 768);
  } else {
#pragma unroll
    for (int p = 0; p < 4; p++) {
      int lv = lengths[sr + p * 32]; if (lv < 1) lv = 1;
      lenp[p] = lv;
    }
#pragma unroll
    for (int i = 0; i < 4; i++)
#pragma unroll
      for (int j = 0; j < 4; j++) pacc[i][j] = (f32x4){0.f, 0.f, 0.f, 0.f};
    // prologue prefetch: t=0 -> wj=0, ki=0, y=64+g
    {
      const int y = 64 + g;
      const int gk = sc;                // ki=0
#pragma unroll
      for (int p = 0; p < 4; p++) {
        const int r = sr + p * 32;
        int ss = y;
        if (d) ss = (y < lenp[p]) ? (lenp[p] - 1 - y) : y;
        pfX[p] = *(const float4*)(XSRC + ((size_t)ss * 128 + r) * K + gk);
        pfW[p] = *(const float4*)(wih + (size_t)(n0 + r) * K + gk);
      }
    }
  }
  __syncthreads();

  for (int t = 0; t < T_; t++) {
    const bool last = (t == T_ - 1);

    // ================= PHASE A =================
    if (is_lstm) {
      // lstm MFMA gate matvec: 48 MFMAs, 6 independent chains
      f32x4 aH0 = {0.f,0.f,0.f,0.f}, aM0 = {0.f,0.f,0.f,0.f}, aL0 = {0.f,0.f,0.f,0.f};
      f32x4 aH1 = {0.f,0.f,0.f,0.f}, aM1 = {0.f,0.f,0.f,0.f}, aL1 = {0.f,0.f,0.f,0.f};
#pragma unroll
      for (int kt = 0; kt < 8; kt++) {
        const int ro = r16 * LDA + kt * 32 + quad * 8;
        bf16x8 ahf = *(const bf16x8*)&Ah[ro];
        bf16x8 alf = *(const bf16x8*)&Al[ro];
        aH0 = MFMA16(ahf, bh[0][kt], aH0);
        aM0 = MFMA16(ahf, bl[0][kt], aM0);
        aL0 = MFMA16(alf, bh[0][kt], aL0);
        aH1 = MFMA16(ahf, bh[1][kt], aH1);
        aM1 = MFMA16(ahf, bl[1][kt], aM1);
        aL1 = MFMA16(alf, bh[1][kt], aL1);
      }
      if (quad < 2) {
#pragma unroll
        for (int reg = 0; reg < 4; reg++) {
          gbuf[(quad * 4 + reg) * 128 + w * 32 + r16]      = aH0[reg] + aM0[reg] + aL0[reg];
          gbuf[(quad * 4 + reg) * 128 + w * 32 + 16 + r16] = aH1[reg] + aM1[reg] + aL1[reg];
        }
      }
    } else {
      // proj: stage prefetched regs -> LDS (k-iter of step t)
      if (t < 192) {
        const int ki = t & 15;
        if (ki < KITERS) {
#pragma unroll
          for (int p = 0; p < 4; p++) {
            const int gk = ki * 32 + sc;
            const int ro = (sr + p * 32) * LDK + sc;
            float4 xv = {0.f,0.f,0.f,0.f}, wv = {0.f,0.f,0.f,0.f};
            if (gk < K) { xv = pfX[p]; wv = pfW[p]; }
            split_f4(xv, &PXh[ro], &PXl[ro]);
            split_f4(wv, &PWh[ro], &PWl[ro]);
          }
        }
      }
    }
    __syncthreads();   // B1: gbuf ready (lstm) / PX,PW staged (proj)

    // ================= PHASE B =================
    if (is_lstm) {
      // cell update
      const float gi = gbuf[cb * 128 +       hl] + x0;
      const float gf = gbuf[cb * 128 +  32 + hl] + x1;
      const float gg = gbuf[cb * 128 +  64 + hl] + x2;
      const float go = gbuf[cb * 128 +  96 + hl] + x3;
      const float si = sigf(gi), sf = sigf(gf);
      const float tg = tanhfast(gg), so = sigf(go);
      c = sf * c + si * tg;
      const float h = so * tanhfast(c);
      if (!last) {
        const unsigned hu = (unsigned)(unsigned short)hi_bf16(h);
        const unsigned lu = (unsigned)(unsigned short)lo_bf16(h);
        const unsigned pv = (hu << 16) | (lu & 0xFFFEu) | (unsigned)((t >> 2) & 1);
        ATOM_ST(&ring32[(((t & 3) * 2 + d) * 128 + b) * 256 + hdim], pv);
      }
      const int tin = d ? ((t < lb) ? (lb - 1 - t) : t) : t;
      hout[((size_t)tin * 128 + b) * 512 + d * 256 + hdim] = h;

      if (!last) {
        // prefetch x(t+1) from xg ring (L3-coherent)
        const int ns = (t + 1) % XGS;
        const float* xn = xgd + ((size_t)ns * 128 + b) * 1024 + hdim;
        const float nx0 = ATOM_LD(xn), nx1 = ATOM_LD(xn + 256);
        const float nx2 = ATOM_LD(xn + 512), nx3 = ATOM_LD(xn + 768);

        // spin on ring (direct data poll, parity check), then restage A
        const unsigned* ru = ring32 + (((t & 3) * 2 + d) * 128 + g * 8 + cb) * 256 + k0;
        const unsigned par = (unsigned)((t >> 2) & 1);
        unsigned uv[8];
        int it = 0;
        for (;;) {
          bool ok = true;
#pragma unroll
          for (int j = 0; j < 8; j++) {
            uv[j] = ATOM_LD(&ru[j]);
            ok &= ((uv[j] & 1u) == par);
          }
          if (ok || ++it >= 100000) break;
        }
        bf16x8 hv, lv;
#pragma unroll
        for (int j = 0; j < 8; j++) {
          hv[j] = (short)(uv[j] >> 16);
          lv[j] = (short)(uv[j] & 0xFFFFu);
        }
        *(bf16x8*)&Ah[cb * LDA + k0] = hv;
        *(bf16x8*)&Al[cb * LDA + k0] = lv;

        x0 = nx0; x1 = nx1; x2 = nx2; x3 = nx3;
      }
    } else {
      // proj: consume LDS -> 48 MFMAs; epilogue at ki==15; prefetch next k-iter
      if (t < 192) {
        const int ki = t & 15;
        if (ki < KITERS) {
          bf16x8 pah[4], pal[4], pbh[4], pbl[4];
#pragma unroll
          for (int mt = 0; mt < 4; mt++) {
            const int ro = (pmb + mt * 16 + pr16) * LDK + pquad * 8;
            pah[mt] = *(const bf16x8*)&PXh[ro];
            pal[mt] = *(const bf16x8*)&PXl[ro];
          }
#pragma unroll
          for (int nt = 0; nt < 4; nt++) {
            const int ro = (pnb + nt * 16 + pr16) * LDK + pquad * 8;
            pbh[nt] = *(const bf16x8*)&PWh[ro];
            pbl[nt] = *(const bf16x8*)&PWl[ro];
          }
#pragma unroll
          for (int mt = 0; mt < 4; mt++)
#pragma unroll
            for (int nt = 0; nt < 4; nt++) {
              pacc[mt][nt] = MFMA16(pah[mt], pbh[nt], pacc[mt][nt]);
              pacc[mt][nt] = MFMA16(pah[mt], pbl[nt], pacc[mt][nt]);
              pacc[mt][nt] = MFMA16(pal[mt], pbh[nt], pacc[mt][nt]);
            }
        }
        if (ki == 15) {
          const int y = 64 + (t >> 4) * 16 + g;
          const int yslot = y % XGS;
          float bsum[4];
#pragma unroll
          for (int nt = 0; nt < 4; nt++) {
            const int col = n0 + pnb + nt * 16 + pr16;
            bsum[nt] = bias1[col] + bias2[col];
          }
#pragma unroll
          for (int mt = 0; mt < 4; mt++) {
            const int row = pmb + mt * 16 + pquad * 4;
#pragma unroll
            for (int nt = 0; nt < 4; nt++) {
              const int col = n0 + pnb + nt * 16 + pr16;
              float* Cp = xgd + ((size_t)yslot * 128 + row) * 1024 + col;
#pragma unroll
              for (int reg = 0; reg < 4; reg++)
                ATOM_ST(&Cp[(size_t)reg * 1024], pacc[mt][nt][reg] + bsum[nt]);
              pacc[mt][nt] = (f32x4){0.f, 0.f, 0.f, 0.f};
            }
          }
        }
      }
      // prefetch for step t+1 (latency hides through B2 + next phase A)
      const int tn = t + 1;
      if (tn < 192) {
        const int kin = tn & 15;
        if (kin < KITERS) {
          const int y = 64 + (tn >> 4) * 16 + g;
          const int gk = kin * 32 + sc;
          if (gk < K) {
#pragma unroll
            for (int p = 0; p < 4; p++) {
              const int r = sr + p * 32;
              int ss = y;
              if (d) ss = (y < lenp[p]) ? (lenp[p] - 1 - y) : y;
              pfX[p] = *(const float4*)(XSRC + ((size_t)ss * 128 + r) * K + gk);
              pfW[p] = *(const float4*)(wih + (size_t)(n0 + r) * K + gk);
            }
          }
        }
      }
    }
    __syncthreads();   // B2: A restaged (lstm) / LDS consumed (proj)
  }
}

// ---------------- masked softmax over t + weighted sum ----------------
__global__ __launch_bounds__(256) void attn_final(
    const float* __restrict__ h2, const float* __restrict__ scores,
    const int* __restrict__ lengths, float* __restrict__ out)
{
  __shared__ float sl[256];
  __shared__ float red[256];
  const int b = blockIdx.x, tid = threadIdx.x;
  int lb = lengths[b]; if (lb < 1) lb = 1;
  const float sc = scores[(size_t)tid * 128 + b];
  const bool valid = (tid < lb);
  red[tid] = valid ? sc : -1e30f;
  __syncthreads();
  for (int off = 128; off > 0; off >>= 1) {
    if (tid < off) red[tid] = fmaxf(red[tid], red[tid + off]);
    __syncthreads();
  }
  const float mx = red[0];
  __syncthreads();
  const float p = valid ? __expf(sc - mx) : 0.f;
  red[tid] = p;
  __syncthreads();
  for (int off = 128; off > 0; off >>= 1) {
    if (tid < off) red[tid] += red[tid + off];
    __syncthreads();
  }
  const float inv = 1.f / red[0];
  __syncthreads();
  sl[tid] = p * inv;
  __syncthreads();

  float ax = 0.f, ay = 0.f;
  const int dd = tid * 2;
  for (int t = 0; t < 256; t++) {
    const float w = sl[t];
    if (w != 0.f) {
      const float* row = h2 + ((size_t)t * 128 + b) * 512 + dd;
      ax += w * row[0];
      ay += w * row[1];
    }
  }
  float2 r; r.x = ax; r.y = ay;
  *(float2*)(out + (size_t)b * 512 + dd) = r;
}

// ---------------- launch ----------------
extern "C" void kernel_launch(void* const* d_in, const int* in_sizes, int n_in,
                              void* d_out, int out_size, void* d_ws, size_t ws_size,
                              hipStream_t stream) {
  (void)in_sizes; (void)n_in; (void)out_size; (void)ws_size;
  const float* x        = (const float*)d_in[0];
  const int*   lengths  = (const int*)d_in[1];
  const float* w_ih_l0  = (const float*)d_in[2];
  const float* w_hh_l0  = (const float*)d_in[3];
  const float* b_ih_l0  = (const float*)d_in[4];
  const float* b_hh_l0  = (const float*)d_in[5];
  const float* w_ih_l0r = (const float*)d_in[6];
  const float* w_hh_l0r = (const float*)d_in[7];
  const float* b_ih_l0r = (const float*)d_in[8];
  const float* b_hh_l0r = (const float*)d_in[9];
  const float* w_ih_l1  = (const float*)d_in[10];
  const float* w_hh_l1  = (const float*)d_in[11];
  const float* b_ih_l1  = (const float*)d_in[12];
  const float* b_hh_l1  = (const float*)d_in[13];
  const float* w_ih_l1r = (const float*)d_in[14];
  const float* w_hh_l1r = (const float*)d_in[15];
  const float* b_ih_l1r = (const float*)d_in[16];
  const float* b_hh_l1r = (const float*)d_in[17];
  const float* mlp_w    = (const float*)d_in[18];
  const float* mlp_b    = (const float*)d_in[19];
  const float* ctx      = (const float*)d_in[20];
  float* out = (float*)d_out;

  // workspace layout (floats): ~215 MB
  float* ws = (float*)d_ws;
  const size_t XG76  = (size_t)XGS * B_ * G4H;        // 9,961,472
  const size_t H_SZ  = (size_t)T_ * B_ * H2;          // 16,777,216
  const size_t RINGF = (size_t)RSLOTS * 2 * B_ * H_;  // 262,144
  float* xgF    = ws;
  float* xgR    = xgF + XG76;
  float* h1     = xgR + XG76;
  float* h2     = h1 + H_SZ;
  float* ring   = h2 + H_SZ;
  float* scores = ring + RINGF;                       // 32,768

  (void)hipMemsetAsync(scores, 0, 32768 * 4, stream);

  dim3 blk(256);
  const dim3 pgrid(G4H / 128, 64, 2);   // standalone proj: y = 0..63, both dirs

  // ---- layer 0 ----
  proj_gemm2<<<pgrid, blk, 0, stream>>>(x, w_ih_l0, w_ih_l0r,
                                        b_ih_l0, b_hh_l0, b_ih_l0r, b_hh_l0r,
                                        xgF, xgR, G4H, D_, lengths, 0);
  (void)hipMemsetAsync(ring, 0xFF, RINGF * 4, stream);   // sentinel (parity=1)
  lstm_fused<<<256, dim3(512), 0, stream>>>(xgF, xgR, x, w_hh_l0, w_hh_l0r,
                                            w_ih_l0, w_ih_l0r,
                                            b_ih_l0, b_hh_l0, b_ih_l0r, b_hh_l0r,
                                            lengths, h1, ring, D_);
  // ---- layer 1 ----
  proj_gemm2<<<pgrid, blk, 0, stream>>>(h1, w_ih_l1, w_ih_l1r,
                                        b_ih_l1, b_hh_l1, b_ih_l1r, b_hh_l1r,
                                        xgF, xgR, G4H, H2, lengths, 0);
  (void)hipMemsetAsync(ring, 0xFF, RINGF * 4, stream);
  lstm_fused<<<256, dim3(512), 0, stream>>>(xgF, xgR, h1, w_hh_l1, w_hh_l1r,
                                            w_ih_l1, w_ih_l1r,
                                            b_ih_l1, b_hh_l1, b_ih_l1r, b_hh_l1r,
                                            lengths, h2, ring, H2);
  // ---- attention ----
  attn_gemm<<<dim3(H2 / 128, (T_ * B_) / 128), blk, 0, stream>>>(h2, mlp_w, mlp_b, ctx, scores, T_ * B_, H2, H2);
  attn_final<<<B_, blk, 0, stream>>>(h2, scores, lengths, out);
}

// Round 11
// 2235.132 us; speedup vs baseline: 1.6920x; 1.6782x over previous
//
#include <hip/hip_runtime.h>

// SentenceEncodingRNN2: 2-layer BiLSTM (T=256,B=128,D=300,H=256) + attention pooling.
// Round 20: block-specialized fusion. R18/R19 post-mortem: per-iteration wave-split
//   keeps BOTH paths' registers live across the loop -> demand ~260 > 256 cap of an
//   8-wave block -> spills (VGPR=128, WRITE 1.5GB). Fix: proj in SEPARATE BLOCKS.
//   Blocks 0..255: exact R11 lstm protocol (4 waves, 128-VGPR weights, parity ring,
//   64-step chunk). Blocks 256..511: proj engine, 4 tile-jobs each = next chunk's
//   proj, epilogue gated on per-(d,g) lstm progress counters (write slot y%76 only
//   when min_prog >= y-74; WAR-safe). Disjoint top-level branches -> VGPR = max not
//   sum. 512 blocks x 61KB LDS = 2 blocks/CU, all resident. Parity ring carried
//   across chunks (no bbuf, no 16MB memsets; ring+prog reset per layer).
//   Standalone warmup proj y=0..63 per layer; attn_gemm/attn_final unchanged.

#define T_ 256
#define B_ 128
#define D_ 300
#define H_ 256
#define G4H 1024   // 4*H
#define H2 512     // 2*H
#define TC 64      // time-chunk length
#define LDK 40     // proj/attn LDS k-stride in bf16 (80 B rows)
#define LDA 264    // lstm A-tile LDS k-stride in bf16 (256+8)
#define XGS 76     // xg ring slots
#define RSLOTS 4   // h-exchange ring slots

typedef __attribute__((ext_vector_type(8))) short bf16x8;
typedef __attribute__((ext_vector_type(4))) short short4v;
typedef __attribute__((ext_vector_type(4))) float f32x4;

#define MFMA16(a, b, c) __builtin_amdgcn_mfma_f32_16x16x32_bf16(a, b, c, 0, 0, 0)
#define ATOM_ST(p, v) __hip_atomic_store((p), (v), __ATOMIC_RELAXED, __HIP_MEMORY_SCOPE_AGENT)
#define ATOM_LD(p) __hip_atomic_load((p), __ATOMIC_RELAXED, __HIP_MEMORY_SCOPE_AGENT)

// ---------------- helpers ----------------
__device__ __forceinline__ float sigf(float x) { return 1.f / (1.f + __expf(-x)); }
__device__ __forceinline__ float tanhfast(float x) { return 2.f / (1.f + __expf(-2.f * x)) - 1.f; }

__device__ __forceinline__ short hi_bf16(float x) {
  return (short)(__float_as_uint(x) >> 16);
}
__device__ __forceinline__ short lo_bf16(float x) {
  float lo = x - __uint_as_float(__float_as_uint(x) & 0xFFFF0000u);
  return (short)(__float_as_uint(lo) >> 16);
}

__device__ __forceinline__ void split_f4(const float4 v, short* hp, short* lp) {
  short4v h, l;
  h.x = hi_bf16(v.x); l.x = lo_bf16(v.x);
  h.y = hi_bf16(v.y); l.y = lo_bf16(v.y);
  h.z = hi_bf16(v.z); l.z = lo_bf16(v.z);
  h.w = hi_bf16(v.w); l.w = lo_bf16(v.w);
  *(short4v*)hp = h;
  *(short4v*)lp = l;
}

__device__ __forceinline__ void split8(const float4 v0, const float4 v1,
                                       bf16x8* hp, bf16x8* lp) {
  bf16x8 h, l;
  h[0] = hi_bf16(v0.x); l[0] = lo_bf16(v0.x);
  h[1] = hi_bf16(v0.y); l[1] = lo_bf16(v0.y);
  h[2] = hi_bf16(v0.z); l[2] = lo_bf16(v0.z);
  h[3] = hi_bf16(v0.w); l[3] = lo_bf16(v0.w);
  h[4] = hi_bf16(v1.x); l[4] = lo_bf16(v1.x);
  h[5] = hi_bf16(v1.y); l[5] = lo_bf16(v1.y);
  h[6] = hi_bf16(v1.z); l[6] = lo_bf16(v1.z);
  h[7] = hi_bf16(v1.w); l[7] = lo_bf16(v1.w);
  *hp = h; *lp = l;
}

// ---------------- dual-direction projection GEMM (standalone, y=0..63) -----------
__global__ __launch_bounds__(256, 2) void proj_gemm2(
    const float* __restrict__ X,
    const float* __restrict__ W0, const float* __restrict__ W1,
    const float* __restrict__ b1f, const float* __restrict__ b2f,
    const float* __restrict__ b1r, const float* __restrict__ b2r,
    float* __restrict__ C0, float* __restrict__ C1,
    int N, int K, const int* __restrict__ lengths, int t0)
{
  __shared__ short Xh[128 * LDK], Xl[128 * LDK];
  __shared__ short Wh[128 * LDK], Wl[128 * LDK];
  const int rev = blockIdx.z;
  const float* __restrict__ W = rev ? W1 : W0;
  const float* __restrict__ bias1 = rev ? b1r : b1f;
  const float* __restrict__ bias2 = rev ? b2r : b2f;
  float* __restrict__ C = rev ? C1 : C0;

  const int tid = threadIdx.x;
  const int m0 = blockIdx.y * 128, n0 = blockIdx.x * 128;
  const int s_step = t0 + blockIdx.y;

  const int sr = tid >> 3;
  const int sc = (tid & 7) * 4;
  const float* px[4];
  const float* pw[4];
#pragma unroll
  for (int p = 0; p < 4; p++) {
    const int r = sr + p * 32;          // r == batch index within tile
    int ss = s_step;
    if (rev) {
      int lb = lengths[r]; if (lb < 1) lb = 1;
      ss = (s_step < lb) ? (lb - 1 - s_step) : s_step;
    }
    px[p] = X + (size_t)(ss * 128 + r) * K;
    pw[p] = W + (size_t)(n0 + r) * K;
  }

  const int lane = tid & 63, w = tid >> 6;
  const int mb = (w & 1) * 64, nb = (w >> 1) * 64;
  const int r16 = lane & 15, quad = lane >> 4;

  f32x4 acc[4][4];
#pragma unroll
  for (int i = 0; i < 4; i++)
#pragma unroll
    for (int j = 0; j < 4; j++) acc[i][j] = (f32x4){0.f, 0.f, 0.f, 0.f};

  for (int k0 = 0; k0 < K; k0 += 32) {
    const int gk = k0 + sc;
    const bool kin = (gk < K);          // K % 4 == 0 -> whole float4 in/out
#pragma unroll
    for (int p = 0; p < 4; p++) {
      float4 xv = {0.f, 0.f, 0.f, 0.f}, wv = {0.f, 0.f, 0.f, 0.f};
      if (kin) { xv = *(const float4*)(px[p] + gk); wv = *(const float4*)(pw[p] + gk); }
      const int ro = (sr + p * 32) * LDK + sc;
      split_f4(xv, &Xh[ro], &Xl[ro]);
      split_f4(wv, &Wh[ro], &Wl[ro]);
    }
    __syncthreads();

    bf16x8 ah[4], al[4], bh[4], bl[4];
#pragma unroll
    for (int mt = 0; mt < 4; mt++) {
      const int ro = (mb + mt * 16 + r16) * LDK + quad * 8;
      ah[mt] = *(const bf16x8*)&Xh[ro];
      al[mt] = *(const bf16x8*)&Xl[ro];
    }
#pragma unroll
    for (int nt = 0; nt < 4; nt++) {
      const int ro = (nb + nt * 16 + r16) * LDK + quad * 8;
      bh[nt] = *(const bf16x8*)&Wh[ro];
      bl[nt] = *(const bf16x8*)&Wl[ro];
    }
#pragma unroll
    for (int mt = 0; mt < 4; mt++)
#pragma unroll
      for (int nt = 0; nt < 4; nt++) {
        acc[mt][nt] = __builtin_amdgcn_mfma_f32_16x16x32_bf16(ah[mt], bh[nt], acc[mt][nt], 0, 0, 0);
        acc[mt][nt] = __builtin_amdgcn_mfma_f32_16x16x32_bf16(ah[mt], bl[nt], acc[mt][nt], 0, 0, 0);
        acc[mt][nt] = __builtin_amdgcn_mfma_f32_16x16x32_bf16(al[mt], bh[nt], acc[mt][nt], 0, 0, 0);
      }
    __syncthreads();
  }

  float bsum[4];
#pragma unroll
  for (int nt = 0; nt < 4; nt++) {
    const int col = n0 + nb + nt * 16 + r16;
    bsum[nt] = bias1[col] + bias2[col];
  }
#pragma unroll
  for (int mt = 0; mt < 4; mt++) {
    const int row = m0 + mb + mt * 16 + quad * 4;
#pragma unroll
    for (int nt = 0; nt < 4; nt++) {
      const int col = n0 + nb + nt * 16 + r16;
      float* Cp = C + (size_t)row * N + col;
#pragma unroll
      for (int reg = 0; reg < 4; reg++)
        Cp[(size_t)reg * N] = acc[mt][nt][reg] + bsum[nt];
    }
  }
}

// ---------------- attention score GEMM, split-bf16 MFMA, fused tanh*ctx ----------
__global__ __launch_bounds__(256, 2) void attn_gemm(
    const float* __restrict__ X, const float* __restrict__ W,
    const float* __restrict__ mlp_b, const float* __restrict__ ctx,
    float* __restrict__ scores, int M, int N, int K)
{
  __shared__ short Xh[128 * LDK], Xl[128 * LDK];
  __shared__ short Wh[128 * LDK], Wl[128 * LDK];
  const int tid = threadIdx.x;
  const int m0 = blockIdx.y * 128, n0 = blockIdx.x * 128;

  const int sr = tid >> 3;
  const int sc = (tid & 7) * 4;
  const float* px[4];
  const float* pw[4];
#pragma unroll
  for (int p = 0; p < 4; p++) {
    px[p] = X + (size_t)(m0 + sr + p * 32) * K;
    pw[p] = W + (size_t)(n0 + sr + p * 32) * K;
  }

  const int lane = tid & 63, w = tid >> 6;
  const int mb = (w & 1) * 64, nb = (w >> 1) * 64;
  const int r16 = lane & 15, quad = lane >> 4;

  f32x4 acc[4][4];
#pragma unroll
  for (int i = 0; i < 4; i++)
#pragma unroll
    for (int j = 0; j < 4; j++) acc[i][j] = (f32x4){0.f, 0.f, 0.f, 0.f};

  for (int k0 = 0; k0 < K; k0 += 32) {
    const int gk = k0 + sc;
#pragma unroll
    for (int p = 0; p < 4; p++) {
      float4 xv = *(const float4*)(px[p] + gk);
      float4 wv = *(const float4*)(pw[p] + gk);
      const int ro = (sr + p * 32) * LDK + sc;
      split_f4(xv, &Xh[ro], &Xl[ro]);
      split_f4(wv, &Wh[ro], &Wl[ro]);
    }
    __syncthreads();

    bf16x8 ah[4], al[4], bh[4], bl[4];
#pragma unroll
    for (int mt = 0; mt < 4; mt++) {
      const int ro = (mb + mt * 16 + r16) * LDK + quad * 8;
      ah[mt] = *(const bf16x8*)&Xh[ro];
      al[mt] = *(const bf16x8*)&Xl[ro];
    }
#pragma unroll
    for (int nt = 0; nt < 4; nt++) {
      const int ro = (nb + nt * 16 + r16) * LDK + quad * 8;
      bh[nt] = *(const bf16x8*)&Wh[ro];
      bl[nt] = *(const bf16x8*)&Wl[ro];
    }
#pragma unroll
    for (int mt = 0; mt < 4; mt++)
#pragma unroll
      for (int nt = 0; nt < 4; nt++) {
        acc[mt][nt] = __builtin_amdgcn_mfma_f32_16x16x32_bf16(ah[mt], bh[nt], acc[mt][nt], 0, 0, 0);
        acc[mt][nt] = __builtin_amdgcn_mfma_f32_16x16x32_bf16(ah[mt], bl[nt], acc[mt][nt], 0, 0, 0);
        acc[mt][nt] = __builtin_amdgcn_mfma_f32_16x16x32_bf16(al[mt], bh[nt], acc[mt][nt], 0, 0, 0);
      }
    __syncthreads();
  }

  float bb4[4], cc4[4];
#pragma unroll
  for (int nt = 0; nt < 4; nt++) {
    const int col = n0 + nb + nt * 16 + r16;
    bb4[nt] = mlp_b[col];
    cc4[nt] = ctx[col];
  }
#pragma unroll
  for (int mt = 0; mt < 4; mt++) {
#pragma unroll
    for (int reg = 0; reg < 4; reg++) {
      float ssum = 0.f;
#pragma unroll
      for (int nt = 0; nt < 4; nt++)
        ssum += tanhfast(acc[mt][nt][reg] + bb4[nt]) * cc4[nt];
      ssum += __shfl_xor(ssum, 1);
      ssum += __shfl_xor(ssum, 2);
      ssum += __shfl_xor(ssum, 4);
      ssum += __shfl_xor(ssum, 8);
      if (r16 == 0)
        atomicAdd(&scores[m0 + mb + mt * 16 + quad * 4 + reg], ssum);
    }
  }
}

// ---------------- fused: lstm blocks (0..255) + proj blocks (256..511) -----------
// lstm blk = s*32 + d*16 + g; chunk [t0, t0+TC). Parity h-ring (4 slots) carried
// across chunks; cbuf for c-state; x from 76-slot xg ring.
// Progress: prog[d*16+g] = t-1 published at top of iteration t by (s==0, tid==0);
//   semantics: all blocks of group consumed x(<=t-1).
// proj block p (0..255): jobs J = p + 256*jj; nd=J&15 -> n0=(nd>>1)*128, dir=nd&1;
//   yy=J>>4; y = t0+64+yy. Compute ungated; epilogue gated on
//   min_g prog[dir][g] >= y-74, writes xg ring slot y%76.
__global__ __launch_bounds__(256, 2) void lstm_fused(
    float* __restrict__ xgF, float* __restrict__ xgR,
    const float* __restrict__ XSRC,
    const float* __restrict__ whF, const float* __restrict__ whR,
    const float* __restrict__ wihF, const float* __restrict__ wihR,
    const float* __restrict__ b1f, const float* __restrict__ b2f,
    const float* __restrict__ b1r, const float* __restrict__ b2r,
    const int* __restrict__ lengths, float* __restrict__ hout,
    float* __restrict__ ring, float* __restrict__ cbuf,
    int* __restrict__ prog, int t0, int K, int do_proj)
{
  __shared__ short Ah[16 * LDA], Al[16 * LDA];
  __shared__ float gbuf[8 * 128];
  __shared__ short PXh[128 * LDK], PXl[128 * LDK];
  __shared__ short PWh[128 * LDK], PWl[128 * LDK];
  __shared__ int gflag;

  const int tid = threadIdx.x;
  unsigned* __restrict__ ring32 = (unsigned*)ring;

  if (blockIdx.x < 256) {
    // ================= LSTM role =================
    const int blk = blockIdx.x;
    const int s = blk >> 5;
    const int d = (blk >> 4) & 1;
    const int g = blk & 15;
    float* __restrict__ xgd = d ? xgR : xgF;
    const float* __restrict__ wh = d ? whR : whF;

    const int lane = tid & 63;
    const int w = tid >> 6;            // wave == gate
    const int r16 = lane & 15, quad = lane >> 4;
    const int cb = tid >> 5;           // 0..7
    const int hl = tid & 31;
    const int b = g * 8 + cb;
    const int hdim = s * 32 + hl;
    const int k0 = hl * 8;

    // weights (hi/lo bf16): 128 VGPR, statically indexed
    bf16x8 bh[2][8], bl[2][8];
#pragma unroll
    for (int nt = 0; nt < 2; nt++)
#pragma unroll
      for (int kt = 0; kt < 8; kt++) {
        const float* wr = wh + (size_t)(w * 256 + s * 32 + nt * 16 + r16) * 256
                             + kt * 32 + quad * 8;
        float4 v0 = *(const float4*)(wr);
        float4 v1 = *(const float4*)(wr + 4);
        split8(v0, v1, &bh[nt][kt], &bl[nt][kt]);
      }

    // zero pad rows 8..15 (always)
    {
      int* za = (int*)(Ah + 8 * LDA);
      int* zb = (int*)(Al + 8 * LDA);
      for (int i = tid; i < (8 * LDA) / 2; i += 256) { za[i] = 0; zb[i] = 0; }
    }

    float c;
    if (t0 == 0) {
      int* za = (int*)Ah;
      int* zb = (int*)Al;
      for (int i = tid; i < (8 * LDA) / 2; i += 256) { za[i] = 0; zb[i] = 0; }
      c = 0.f;
    } else {
      c = cbuf[((size_t)d * 128 + b) * 256 + hdim];
      // initial A = h(t0-1) from parity ring (written by previous dispatch)
      const int pslot = (t0 - 1) & 3;
      const unsigned par = (unsigned)(((t0 - 1) >> 2) & 1);
      const unsigned* ru = ring32 + (((size_t)pslot * 2 + d) * 128 + g * 8 + cb) * 256 + k0;
      unsigned uv[8];
      int it = 0;
      for (;;) {
        bool ok = true;
#pragma unroll
        for (int j = 0; j < 8; j++) {
          uv[j] = ATOM_LD(&ru[j]);
          ok &= ((uv[j] & 1u) == par);
        }
        if (ok || ++it >= 100000) break;
      }
      bf16x8 hv, lv;
#pragma unroll
      for (int j = 0; j < 8; j++) {
        hv[j] = (short)(uv[j] >> 16);
        lv[j] = (short)(uv[j] & 0xFFFFu);
      }
      *(bf16x8*)&Ah[cb * LDA + k0] = hv;
      *(bf16x8*)&Al[cb * LDA + k0] = lv;
    }
    int lb = lengths[b]; if (lb < 1) lb = 1;

    // initial x from xg ring slot t0%XGS
    {
      const float* xr0 = xgd + ((size_t)(t0 % XGS) * 128 + b) * 1024 + hdim;
      // loaded below into x0..x3
    }
    const float* xr0 = xgd + ((size_t)(t0 % XGS) * 128 + b) * 1024 + hdim;
    float x0 = ATOM_LD(xr0), x1 = ATOM_LD(xr0 + 256);
    float x2 = ATOM_LD(xr0 + 512), x3 = ATOM_LD(xr0 + 768);
    __syncthreads();

    const int tend = t0 + TC;
    for (int t = t0; t < tend; t++) {
      // publish: all threads completed step t-1 (trailing barrier of t-1)
      if (t > t0 && s == 0 && tid == 0) ATOM_ST(&prog[d * 16 + g], t - 1);
      const bool chend = (t == tend - 1);

      // MFMA gate matvec: 48 MFMAs, 6 independent chains
      f32x4 aH0 = {0.f,0.f,0.f,0.f}, aM0 = {0.f,0.f,0.f,0.f}, aL0 = {0.f,0.f,0.f,0.f};
      f32x4 aH1 = {0.f,0.f,0.f,0.f}, aM1 = {0.f,0.f,0.f,0.f}, aL1 = {0.f,0.f,0.f,0.f};
#pragma unroll
      for (int kt = 0; kt < 8; kt++) {
        const int ro = r16 * LDA + kt * 32 + quad * 8;
        bf16x8 ahf = *(const bf16x8*)&Ah[ro];
        bf16x8 alf = *(const bf16x8*)&Al[ro];
        aH0 = MFMA16(ahf, bh[0][kt], aH0);
        aM0 = MFMA16(ahf, bl[0][kt], aM0);
        aL0 = MFMA16(alf, bh[0][kt], aL0);
        aH1 = MFMA16(ahf, bh[1][kt], aH1);
        aM1 = MFMA16(ahf, bl[1][kt], aM1);
        aL1 = MFMA16(alf, bh[1][kt], aL1);
      }
      if (quad < 2) {
#pragma unroll
        for (int reg = 0; reg < 4; reg++) {
          gbuf[(quad * 4 + reg) * 128 + w * 32 + r16]      = aH0[reg] + aM0[reg] + aL0[reg];
          gbuf[(quad * 4 + reg) * 128 + w * 32 + 16 + r16] = aH1[reg] + aM1[reg] + aL1[reg];
        }
      }
      __syncthreads();   // gbuf ready; A reads complete

      // cell update
      const float gi = gbuf[cb * 128 +       hl] + x0;
      const float gf = gbuf[cb * 128 +  32 + hl] + x1;
      const float gg = gbuf[cb * 128 +  64 + hl] + x2;
      const float go = gbuf[cb * 128 +  96 + hl] + x3;
      const float si = sigf(gi), sf = sigf(gf);
      const float tg = tanhfast(gg), so = sigf(go);
      c = sf * c + si * tg;
      const float h = so * tanhfast(c);
      if (t != T_ - 1) {
        const unsigned hu = (unsigned)(unsigned short)hi_bf16(h);
        const unsigned lu = (unsigned)(unsigned short)lo_bf16(h);
        const unsigned pv = (hu << 16) | (lu & 0xFFFEu) | (unsigned)((t >> 2) & 1);
        ATOM_ST(&ring32[(((size_t)(t & 3) * 2 + d) * 128 + b) * 256 + hdim], pv);
      }
      const int tin = d ? ((t < lb) ? (lb - 1 - t) : t) : t;
      hout[((size_t)tin * 128 + b) * 512 + d * 256 + hdim] = h;

      if (!chend) {
        // prefetch x(t+1)
        const int ns = (t + 1) % XGS;
        const float* xn = xgd + ((size_t)ns * 128 + b) * 1024 + hdim;
        const float nx0 = ATOM_LD(xn), nx1 = ATOM_LD(xn + 256);
        const float nx2 = ATOM_LD(xn + 512), nx3 = ATOM_LD(xn + 768);

        // spin on parity ring for h(t), restage A
        const unsigned* ru = ring32 + (((size_t)(t & 3) * 2 + d) * 128 + g * 8 + cb) * 256 + k0;
        const unsigned par = (unsigned)((t >> 2) & 1);
        unsigned uv[8];
        int it = 0;
        for (;;) {
          bool ok = true;
#pragma unroll
          for (int j = 0; j < 8; j++) {
            uv[j] = ATOM_LD(&ru[j]);
            ok &= ((uv[j] & 1u) == par);
          }
          if (ok || ++it >= 100000) break;
        }
        bf16x8 hv, lv;
#pragma unroll
        for (int j = 0; j < 8; j++) {
          hv[j] = (short)(uv[j] >> 16);
          lv[j] = (short)(uv[j] & 0xFFFFu);
        }
        *(bf16x8*)&Ah[cb * LDA + k0] = hv;
        *(bf16x8*)&Al[cb * LDA + k0] = lv;

        x0 = nx0; x1 = nx1; x2 = nx2; x3 = nx3;
        __syncthreads();   // A staged for t+1
      }
    }
    cbuf[((size_t)d * 128 + b) * 256 + hdim] = c;

  } else {
    // ================= PROJ role =================
    if (!do_proj) return;
    const int p = blockIdx.x - 256;
    const int sr = tid >> 3;
    const int sc = (tid & 7) * 4;
    const int lane = tid & 63, w2 = tid >> 6;
    const int mb = (w2 & 1) * 64, nb = (w2 >> 1) * 64;
    const int r16 = lane & 15, quad = lane >> 4;
    const int KITERS = (K + 31) >> 5;

    for (int jj = 0; jj < 4; jj++) {
      const int J = p + 256 * jj;
      const int nd = J & 15;
      const int n0 = (nd >> 1) * 128;
      const int dp = nd & 1;
      const int yy = J >> 4;
      const int y = t0 + 64 + yy;
      float* __restrict__ xgd = dp ? xgR : xgF;
      const float* __restrict__ wih = dp ? wihR : wihF;
      const float* __restrict__ bias1 = dp ? b1r : b1f;
      const float* __restrict__ bias2 = dp ? b2r : b2f;

      const float* px[4];
      const float* pw[4];
#pragma unroll
      for (int q = 0; q < 4; q++) {
        const int r = sr + q * 32;
        int ss = y;
        if (dp) {
          int lbr = lengths[r]; if (lbr < 1) lbr = 1;
          ss = (y < lbr) ? (lbr - 1 - y) : y;
        }
        px[q] = XSRC + (size_t)(ss * 128 + r) * K;
        pw[q] = wih + (size_t)(n0 + r) * K;
      }

      f32x4 acc[4][4];
#pragma unroll
      for (int i = 0; i < 4; i++)
#pragma unroll
        for (int j = 0; j < 4; j++) acc[i][j] = (f32x4){0.f, 0.f, 0.f, 0.f};

      for (int ki = 0; ki < KITERS; ki++) {
        const int gk = ki * 32 + sc;
        const bool kin = (gk < K);
#pragma unroll
        for (int q = 0; q < 4; q++) {
          float4 xv = {0.f, 0.f, 0.f, 0.f}, wv = {0.f, 0.f, 0.f, 0.f};
          if (kin) { xv = *(const float4*)(px[q] + gk); wv = *(const float4*)(pw[q] + gk); }
          const int ro = (sr + q * 32) * LDK + sc;
          split_f4(xv, &PXh[ro], &PXl[ro]);
          split_f4(wv, &PWh[ro], &PWl[ro]);
        }
        __syncthreads();

        bf16x8 ah[4], al[4], wbh[4], wbl[4];
#pragma unroll
        for (int mt = 0; mt < 4; mt++) {
          const int ro = (mb + mt * 16 + r16) * LDK + quad * 8;
          ah[mt] = *(const bf16x8*)&PXh[ro];
          al[mt] = *(const bf16x8*)&PXl[ro];
        }
#pragma unroll
        for (int nt = 0; nt < 4; nt++) {
          const int ro = (nb + nt * 16 + r16) * LDK + quad * 8;
          wbh[nt] = *(const bf16x8*)&PWh[ro];
          wbl[nt] = *(const bf16x8*)&PWl[ro];
        }
#pragma unroll
        for (int mt = 0; mt < 4; mt++)
#pragma unroll
          for (int nt = 0; nt < 4; nt++) {
            acc[mt][nt] = MFMA16(ah[mt], wbh[nt], acc[mt][nt]);
            acc[mt][nt] = MFMA16(ah[mt], wbl[nt], acc[mt][nt]);
            acc[mt][nt] = MFMA16(al[mt], wbh[nt], acc[mt][nt]);
          }
        __syncthreads();
      }

      // gate: safe to overwrite x(y-76) when min_g prog[dp][g] >= y-74
      {
        const int need = y - 74;
        int itg = 0;
        for (;;) {
          if (tid == 0) {
            int m = 0x7fffffff;
#pragma unroll
            for (int i = 0; i < 16; i++) {
              const int v = ATOM_LD(&prog[dp * 16 + i]);
              m = (v < m) ? v : m;
            }
            gflag = (m >= need) ? 1 : 0;
          }
          __syncthreads();
          const int ok = gflag;
          __syncthreads();
          if (ok || ++itg >= 300000) break;
        }
      }

      // epilogue -> xg ring slot y%XGS
      const int yslot = y % XGS;
      float bsum[4];
#pragma unroll
      for (int nt = 0; nt < 4; nt++) {
        const int col = n0 + nb + nt * 16 + r16;
        bsum[nt] = bias1[col] + bias2[col];
      }
#pragma unroll
      for (int mt = 0; mt < 4; mt++) {
        const int row = mb + mt * 16 + quad * 4;
#pragma unroll
        for (int nt = 0; nt < 4; nt++) {
          const int col = n0 + nb + nt * 16 + r16;
          float* Cp = xgd + ((size_t)yslot * 128 + row) * 1024 + col;
#pragma unroll
          for (int reg = 0; reg < 4; reg++)
            ATOM_ST(&Cp[(size_t)reg * 1024], acc[mt][nt][reg] + bsum[nt]);
        }
      }
    }
  }
}

// ---------------- masked softmax over t + weighted sum ----------------
__global__ __launch_bounds__(256) void attn_final(
    const float* __restrict__ h2, const float* __restrict__ scores,
    const int* __restrict__ lengths, float* __restrict__ out)
{
  __shared__ float sl[256];
  __shared__ float red[256];
  const int b = blockIdx.x, tid = threadIdx.x;
  int lb = lengths[b]; if (lb < 1) lb = 1;
  const float sc = scores[(size_t)tid * 128 + b];
  const bool valid = (tid < lb);
  red[tid] = valid ? sc : -1e30f;
  __syncthreads();
  for (int off = 128; off > 0; off >>= 1) {
    if (tid < off) red[tid] = fmaxf(red[tid], red[tid + off]);
    __syncthreads();
  }
  const float mx = red[0];
  __syncthreads();
  const float p = valid ? __expf(sc - mx) : 0.f;
  red[tid] = p;
  __syncthreads();
  for (int off = 128; off > 0; off >>= 1) {
    if (tid < off) red[tid] += red[tid + off];
    __syncthreads();
  }
  const float inv = 1.f / red[0];
  __syncthreads();
  sl[tid] = p * inv;
  __syncthreads();

  float ax = 0.f, ay = 0.f;
  const int dd = tid * 2;
  for (int t = 0; t < 256; t++) {
    const float w = sl[t];
    if (w != 0.f) {
      const float* row = h2 + ((size_t)t * 128 + b) * 512 + dd;
      ax += w * row[0];
      ay += w * row[1];
    }
  }
  float2 r; r.x = ax; r.y = ay;
  *(float2*)(out + (size_t)b * 512 + dd) = r;
}

// ---------------- launch ----------------
extern "C" void kernel_launch(void* const* d_in, const int* in_sizes, int n_in,
                              void* d_out, int out_size, void* d_ws, size_t ws_size,
                              hipStream_t stream) {
  (void)in_sizes; (void)n_in; (void)out_size; (void)ws_size;
  const float* x        = (const float*)d_in[0];
  const int*   lengths  = (const int*)d_in[1];
  const float* w_ih_l0  = (const float*)d_in[2];
  const float* w_hh_l0  = (const float*)d_in[3];
  const float* b_ih_l0  = (const float*)d_in[4];
  const float* b_hh_l0  = (const float*)d_in[5];
  const float* w_ih_l0r = (const float*)d_in[6];
  const float* w_hh_l0r = (const float*)d_in[7];
  const float* b_ih_l0r = (const float*)d_in[8];
  const float* b_hh_l0r = (const float*)d_in[9];
  const float* w_ih_l1  = (const float*)d_in[10];
  const float* w_hh_l1  = (const float*)d_in[11];
  const float* b_ih_l1  = (const float*)d_in[12];
  const float* b_hh_l1  = (const float*)d_in[13];
  const float* w_ih_l1r = (const float*)d_in[14];
  const float* w_hh_l1r = (const float*)d_in[15];
  const float* b_ih_l1r = (const float*)d_in[16];
  const float* b_hh_l1r = (const float*)d_in[17];
  const float* mlp_w    = (const float*)d_in[18];
  const float* mlp_b    = (const float*)d_in[19];
  const float* ctx      = (const float*)d_in[20];
  float* out = (float*)d_out;

  // workspace layout (floats): ~215.3 MB
  float* ws = (float*)d_ws;
  const size_t XGRING = (size_t)XGS * B_ * G4H;       // 9,961,472 per dir
  const size_t H_SZ   = (size_t)T_ * B_ * H2;         // 16,777,216
  const size_t RINGF  = (size_t)RSLOTS * 2 * B_ * H_; // 262,144
  float* xgF    = ws;
  float* xgR    = xgF + XGRING;
  float* h1     = xgR + XGRING;
  float* h2     = h1 + H_SZ;
  float* ring   = h2 + H_SZ;
  float* cbuf   = ring + RINGF;                       // 65,536
  float* scores = cbuf + 65536;                       // 32,768
  int*   prog   = (int*)(scores + 32768);             // 32 ints

  (void)hipMemsetAsync(scores, 0, 32768 * 4, stream);

  dim3 blk(256);
  const dim3 pgrid(G4H / 128, 64, 2);   // standalone proj: y = 0..63, both dirs

  // ==== layer 0 ====
  proj_gemm2<<<pgrid, blk, 0, stream>>>(x, w_ih_l0, w_ih_l0r,
                                        b_ih_l0, b_hh_l0, b_ih_l0r, b_hh_l0r,
                                        xgF, xgR, G4H, D_, lengths, 0);
  (void)hipMemsetAsync(ring, 0xFF, RINGF * 4, stream);   // parity sentinel
  (void)hipMemsetAsync(prog, 0xFF, 32 * 4, stream);      // prog = -1
  for (int c = 0; c < 4; c++) {
    lstm_fused<<<512, blk, 0, stream>>>(xgF, xgR, x, w_hh_l0, w_hh_l0r,
                                        w_ih_l0, w_ih_l0r,
                                        b_ih_l0, b_hh_l0, b_ih_l0r, b_hh_l0r,
                                        lengths, h1, ring, cbuf, prog,
                                        c * TC, D_, (c < 3) ? 1 : 0);
  }
  // ==== layer 1 ====
  proj_gemm2<<<pgrid, blk, 0, stream>>>(h1, w_ih_l1, w_ih_l1r,
                                        b_ih_l1, b_hh_l1, b_ih_l1r, b_hh_l1r,
                                        xgF, xgR, G4H, H2, lengths, 0);
  (void)hipMemsetAsync(ring, 0xFF, RINGF * 4, stream);
  (void)hipMemsetAsync(prog, 0xFF, 32 * 4, stream);
  for (int c = 0; c < 4; c++) {
    lstm_fused<<<512, blk, 0, stream>>>(xgF, xgR, h1, w_hh_l1, w_hh_l1r,
                                        w_ih_l1, w_ih_l1r,
                                        b_ih_l1, b_hh_l1, b_ih_l1r, b_hh_l1r,
                                        lengths, h2, ring, cbuf, prog,
                                        c * TC, H2, (c < 3) ? 1 : 0);
  }
  // ==== attention ====
  attn_gemm<<<dim3(H2 / 128, (T_ * B_) / 128), blk, 0, stream>>>(h2, mlp_w, mlp_b, ctx, scores, T_ * B_, H2, H2);
  attn_final<<<B_, blk, 0, stream>>>(h2, scores, lengths, out);
}